// Round 9
// baseline (6560.463 us; speedup 1.0000x reference)
//
#include <hip/hip_runtime.h>
#include <hip/hip_bf16.h>

#define DOF 69
#define NL 6
#define NH 8
#define DMODEL 512
#define DFF 2048
#define HD 64
#define BB 8
#define TT 512
#define MTOK (BB*TT)   // 4096
#define EROWS 1040     // 2T-1 = 1023, padded

// workspace layout (bytes) — 24.5 MB total
#define E_OFF     4096u
#define H_OFF     (512u*1024u)
#define HN_OFF    (H_OFF + 8u*1024u*1024u)
#define Q_OFF     (HN_OFF + 4u*1024u*1024u)
#define K_OFF     (Q_OFF + 4u*1024u*1024u)
#define V_OFF     (K_OFF + 4u*1024u*1024u)

typedef const float* fp32p;
typedef __hip_bfloat16 bf16;
typedef const bf16* bf16p;
typedef __attribute__((ext_vector_type(8))) short bf16x8;  // 8 bf16 (4 VGPRs)
typedef __attribute__((ext_vector_type(4))) float f32x4;   // 4 fp32 acc

__device__ __forceinline__ float b2f(bf16 x){ return __bfloat162float(x); }

// ---------------- concat(x, mask) fp32 -> bf16 ----------------
__global__ __launch_bounds__(256)
void k_concat(fp32p x, fp32p mask, bf16* __restrict__ out){
    int idx = blockIdx.x*256 + threadIdx.x;
    if (idx >= MTOK*2*DOF) return;
    int row = idx / (2*DOF), c = idx - row*(2*DOF);
    float v = (c < DOF) ? x[(size_t)row*DOF + c] : mask[(size_t)row*DOF + (c-DOF)];
    out[idx] = __float2bfloat16(v);
}

// ---------------- cast fp32 -> bf16 ----------------
__global__ __launch_bounds__(256)
void k_cast(const float* __restrict__ in, bf16* __restrict__ out){
    int idx = blockIdx.x*256 + threadIdx.x;
    if (idx >= MTOK*DMODEL) return;
    out[idx] = __float2bfloat16(in[idx]);
}

// ---------------- MFMA GEMM: C = epi(A @ B[boff..] + bias[biasoff..]) ----------------
// A: bf16 (M x K) lda, M % 128 == 0.  B: fp32 weights (K x N) ldb + element offset.
// 128x128 tile, BK=32, 4 waves x (64x64). LDS K-contiguous, pitch 40 (2-way banks, free).
template<int PRELU, int RESID, int HASBIAS, int OUTF32>
__global__ __launch_bounds__(256)
void k_gemm(bf16p A, int lda,
            fp32p Bw, size_t boff, int ldb,
            fp32p bias, size_t biasoff,
            fp32p alpha, size_t aidx,
            const float* __restrict__ resid,
            void* __restrict__ Cout, int ldc,
            int M, int N, int K)
{
    __shared__ bf16 sA[128][40];
    __shared__ bf16 sB[128][40];   // sB[n][k]

    const int tid  = threadIdx.x;
    const int w    = tid >> 6;
    const int lane = tid & 63;
    const int qd   = lane >> 4;       // quad 0..3
    const int cl   = lane & 15;       // 0..15
    const int bm   = blockIdx.y * 128;
    const int bn   = blockIdx.x * 128;
    const int mbase = (w & 1) * 64;
    const int nbase = (w >> 1) * 64;

    // staging indices
    const int srow = tid >> 1;            // 0..127
    const int kh   = (tid & 1) * 16;      // 0 or 16

    f32x4 acc[4][4] = {};

    const bool ldaVec = ((lda & 7) == 0);

    for (int k0 = 0; k0 < K; k0 += 32) {
        // ---- stage A: rows bm+srow, k = k0+kh .. +16 ----
        {
            const bf16* ar = A + (size_t)(bm + srow)*lda + k0 + kh;
            bf16 tmp[16];
            if (ldaVec && (k0 + kh + 16 <= K)) {
                bf16x8 v0 = *(const bf16x8*)(ar);
                bf16x8 v1 = *(const bf16x8*)(ar + 8);
                *(bf16x8*)&tmp[0] = v0; *(bf16x8*)&tmp[8] = v1;
            } else {
                #pragma unroll
                for (int e = 0; e < 16; ++e)
                    tmp[e] = (k0 + kh + e < K) ? ar[e] : __float2bfloat16(0.f);
            }
            *(bf16x8*)&sA[srow][kh]     = *(bf16x8*)&tmp[0];
            *(bf16x8*)&sA[srow][kh + 8] = *(bf16x8*)&tmp[8];
        }
        // ---- stage B: col bn+srow (n), k = k0+kh .. +16, fp32 -> bf16 ----
        {
            const int n = srow;
            bf16 tmp[16];
            if (bn + n < N) {
                const float* br = Bw + boff + (size_t)(k0 + kh)*ldb + bn + n;
                #pragma unroll
                for (int e = 0; e < 16; ++e) {
                    float vv = (k0 + kh + e < K) ? br[(size_t)e*ldb] : 0.f;
                    tmp[e] = __float2bfloat16(vv);
                }
            } else {
                #pragma unroll
                for (int e = 0; e < 16; ++e) tmp[e] = __float2bfloat16(0.f);
            }
            *(bf16x8*)&sB[n][kh]     = *(bf16x8*)&tmp[0];
            *(bf16x8*)&sB[n][kh + 8] = *(bf16x8*)&tmp[8];
        }
        __syncthreads();

        // ---- compute: 16 MFMA per wave ----
        bf16x8 aF[4], bF[4];
        #pragma unroll
        for (int mt = 0; mt < 4; ++mt)
            aF[mt] = *(const bf16x8*)&sA[mbase + mt*16 + cl][qd*8];
        #pragma unroll
        for (int nt = 0; nt < 4; ++nt)
            bF[nt] = *(const bf16x8*)&sB[nbase + nt*16 + cl][qd*8];
        #pragma unroll
        for (int mt = 0; mt < 4; ++mt)
            #pragma unroll
            for (int nt = 0; nt < 4; ++nt)
                acc[mt][nt] = __builtin_amdgcn_mfma_f32_16x16x32_bf16(aF[mt], bF[nt], acc[mt][nt], 0, 0, 0);
        __syncthreads();
    }

    // ---- epilogue ----
    const float alp = PRELU ? alpha[aidx] : 0.f;
    #pragma unroll
    for (int mt = 0; mt < 4; ++mt) {
        #pragma unroll
        for (int nt = 0; nt < 4; ++nt) {
            int col = bn + nbase + nt*16 + cl;
            if (col < N) {
                #pragma unroll
                for (int r = 0; r < 4; ++r) {
                    int row = bm + mbase + mt*16 + qd*4 + r;
                    float c = acc[mt][nt][r];
                    if (HASBIAS) c += bias[biasoff + col];
                    if (PRELU) c = (c >= 0.f) ? c : alp*c;
                    if (RESID) c += resid[(size_t)row*ldc + col];
                    if (OUTF32) ((float*)Cout)[(size_t)row*ldc + col] = c;
                    else ((bf16*)Cout)[(size_t)row*ldc + col] = __float2bfloat16(c);
                }
            }
        }
    }
}

// ---------------- LayerNorm: fp32 in -> bf16 out ----------------
__global__ __launch_bounds__(256)
void k_layernorm(const float* __restrict__ x, fp32p g, fp32p b, bf16* __restrict__ out){
    __shared__ float red[256];
    const int row = blockIdx.x, tid = threadIdx.x;
    const float* xr = x + (size_t)row*DMODEL;
    float x0 = xr[tid], x1 = xr[tid+256];
    red[tid] = x0 + x1; __syncthreads();
    for (int o = 128; o > 0; o >>= 1) { if (tid < o) red[tid] += red[tid+o]; __syncthreads(); }
    float mean = red[0] * (1.f/DMODEL);
    __syncthreads();
    float d0 = x0 - mean, d1 = x1 - mean;
    red[tid] = d0*d0 + d1*d1; __syncthreads();
    for (int o = 128; o > 0; o >>= 1) { if (tid < o) red[tid] += red[tid+o]; __syncthreads(); }
    float inv = rsqrtf(red[0]*(1.f/DMODEL) + 1e-6f);
    out[(size_t)row*DMODEL + tid]     = __float2bfloat16(d0*inv*g[tid]     + b[tid]);
    out[(size_t)row*DMODEL + tid+256] = __float2bfloat16(d1*inv*g[tid+256] + b[tid+256]);
}

// ---------------- relative embedding E: (EROWS, HD) bf16, zero-padded ----------------
__global__ __launch_bounds__(64)
void k_relemb(fp32p w1, fp32p b1, fp32p a, fp32p w2, fp32p b2, bf16* __restrict__ Ebf){
    __shared__ float sH[DMODEL];
    const int r = blockIdx.x, tid = threadIdx.x;
    if (r >= 2*TT - 1) { Ebf[(size_t)r*HD + tid] = __float2bfloat16(0.f); return; }
    const float dist = (float)(r - (TT-1));
    const float al = a[0];
    for (int d = tid; d < DMODEL; d += 64) {
        float hv = dist * w1[d] + b1[d];
        sH[d] = (hv >= 0.f) ? hv : al*hv;
    }
    __syncthreads();
    float acc = b2[tid];
    for (int d = 0; d < DMODEL; ++d) acc += sH[d] * w2[(size_t)d*HD + tid];
    Ebf[(size_t)r*HD + tid] = __float2bfloat16(acc);
}

// ---------------- MFMA flash attention with relative-position skew ----------------
__global__ __launch_bounds__(256)
void k_attn(bf16p q, bf16p k, bf16p v, bf16p Ebf, bf16* __restrict__ o)
{
    __shared__ bf16  sVT[64][68];        // V^T tile: [d][j_local]
    __shared__ float sQE[4][16][100];    // per-wave qe tile
    __shared__ bf16  sP[4][16][68];      // per-wave P tile

    const int bid  = blockIdx.x;
    const int itile = bid & 7;
    const int h    = (bid >> 3) & 7;
    const int b    = bid >> 6;
    const int tid  = threadIdx.x;
    const int w    = tid >> 6;
    const int lane = tid & 63;
    const int qd   = lane >> 4;
    const int cl   = lane & 15;

    const int I = itile*64 + w*16;
    const size_t bh = ((size_t)b*TT)*DMODEL + (size_t)h*HD;

    bf16x8 qa0, qa1;
    {
        const bf16* qrow = q + bh + (size_t)(I + cl)*DMODEL;
        qa0 = *(const bf16x8*)(qrow + qd*8);
        qa1 = *(const bf16x8*)(qrow + 32 + qd*8);
    }

    f32x4 Oacc[4] = {};
    float m_i[4], l_i[4];
    #pragma unroll
    for (int r = 0; r < 4; ++r) { m_i[r] = -1e30f; l_i[r] = 0.f; }
    const float scale = 0.125f;

    for (int J = 0; J < TT; J += 64) {
        {
            int j = tid >> 2, dc = (tid & 3) * 16;
            const bf16* vrow = v + bh + (size_t)(J + j)*DMODEL + dc;
            bf16x8 v0 = *(const bf16x8*)(vrow);
            bf16x8 v1 = *(const bf16x8*)(vrow + 8);
            #pragma unroll
            for (int e = 0; e < 8; ++e) sVT[dc + e][j]     = ((const bf16*)&v0)[e];
            #pragma unroll
            for (int e = 0; e < 8; ++e) sVT[dc + 8 + e][j] = ((const bf16*)&v1)[e];
        }
        __syncthreads();

        f32x4 S[4];
        #pragma unroll
        for (int js = 0; js < 4; ++js) {
            const bf16* krow = k + bh + (size_t)(J + js*16 + cl)*DMODEL;
            bf16x8 kb0 = *(const bf16x8*)(krow + qd*8);
            bf16x8 kb1 = *(const bf16x8*)(krow + 32 + qd*8);
            f32x4 acc = {};
            acc = __builtin_amdgcn_mfma_f32_16x16x32_bf16(qa0, kb0, acc, 0, 0, 0);
            acc = __builtin_amdgcn_mfma_f32_16x16x32_bf16(qa1, kb1, acc, 0, 0, 0);
            S[js] = acc;
        }

        const int rbase = J - I + 496;
        #pragma unroll
        for (int nt = 0; nt < 6; ++nt) {
            const bf16* erow = Ebf + (size_t)(rbase + nt*16 + cl)*HD;
            bf16x8 eb0 = *(const bf16x8*)(erow + qd*8);
            bf16x8 eb1 = *(const bf16x8*)(erow + 32 + qd*8);
            f32x4 acc = {};
            acc = __builtin_amdgcn_mfma_f32_16x16x32_bf16(qa0, eb0, acc, 0, 0, 0);
            acc = __builtin_amdgcn_mfma_f32_16x16x32_bf16(qa1, eb1, acc, 0, 0, 0);
            #pragma unroll
            for (int r = 0; r < 4; ++r)
                sQE[w][qd*4 + r][nt*16 + cl] = acc[r];
        }

        float mnew[4];
        #pragma unroll
        for (int r = 0; r < 4; ++r) mnew[r] = m_i[r];
        #pragma unroll
        for (int js = 0; js < 4; ++js) {
            #pragma unroll
            for (int r = 0; r < 4; ++r) {
                int idx = js*16 + cl - (qd*4 + r) + 15;
                float s = S[js][r] + sQE[w][qd*4 + r][idx];
                S[js][r] = s;
                mnew[r] = fmaxf(mnew[r], s);
            }
        }
        #pragma unroll
        for (int r = 0; r < 4; ++r) {
            float mv = mnew[r];
            mv = fmaxf(mv, __shfl_xor(mv, 1));
            mv = fmaxf(mv, __shfl_xor(mv, 2));
            mv = fmaxf(mv, __shfl_xor(mv, 4));
            mv = fmaxf(mv, __shfl_xor(mv, 8));
            mnew[r] = mv;
        }
        float alpha[4], rsum[4];
        #pragma unroll
        for (int r = 0; r < 4; ++r) {
            alpha[r] = expf((m_i[r] - mnew[r]) * scale);
            m_i[r] = mnew[r];
            rsum[r] = 0.f;
        }
        #pragma unroll
        for (int js = 0; js < 4; ++js) {
            #pragma unroll
            for (int r = 0; r < 4; ++r) {
                float p = expf((S[js][r] - m_i[r]) * scale);
                rsum[r] += p;
                sP[w][qd*4 + r][js*16 + cl] = __float2bfloat16(p);
            }
        }
        #pragma unroll
        for (int r = 0; r < 4; ++r) {
            float sv = rsum[r];
            sv += __shfl_xor(sv, 1);
            sv += __shfl_xor(sv, 2);
            sv += __shfl_xor(sv, 4);
            sv += __shfl_xor(sv, 8);
            l_i[r] = l_i[r]*alpha[r] + sv;
        }

        bf16x8 pa0, pa1;
        {
            const bf16* pr = &sP[w][cl][0];
            #pragma unroll
            for (int e = 0; e < 8; ++e) ((short*)&pa0)[e] = ((const short*)pr)[qd*8 + e];
            #pragma unroll
            for (int e = 0; e < 8; ++e) ((short*)&pa1)[e] = ((const short*)pr)[32 + qd*8 + e];
        }

        #pragma unroll
        for (int nt = 0; nt < 4; ++nt) {
            #pragma unroll
            for (int r = 0; r < 4; ++r) Oacc[nt][r] *= alpha[r];
            bf16x8 vb0, vb1;
            const bf16* vr = &sVT[nt*16 + cl][0];
            #pragma unroll
            for (int e = 0; e < 8; ++e) ((short*)&vb0)[e] = ((const short*)vr)[qd*8 + e];
            #pragma unroll
            for (int e = 0; e < 8; ++e) ((short*)&vb1)[e] = ((const short*)vr)[32 + qd*8 + e];
            Oacc[nt] = __builtin_amdgcn_mfma_f32_16x16x32_bf16(pa0, vb0, Oacc[nt], 0, 0, 0);
            Oacc[nt] = __builtin_amdgcn_mfma_f32_16x16x32_bf16(pa1, vb1, Oacc[nt], 0, 0, 0);
        }
        __syncthreads();
    }

    #pragma unroll
    for (int nt = 0; nt < 4; ++nt) {
        #pragma unroll
        for (int r = 0; r < 4; ++r) {
            int row = qd*4 + r;
            float val = Oacc[nt][r] / l_i[r];
            o[bh + (size_t)(I + row)*DMODEL + nt*16 + cl] = __float2bfloat16(val);
        }
    }
}

// ---------------- output split + sigmoid (fp32 out) ----------------
__global__ __launch_bounds__(256)
void k_out(const float* __restrict__ y, float* __restrict__ out){
    int idx = blockIdx.x*256 + threadIdx.x;
    if (idx >= MTOK*73) return;
    int row = idx / 73, c = idx - row*73;
    float val = y[idx];
    if (c < DOF) out[(size_t)row*DOF + c] = val;
    else out[(size_t)MTOK*DOF + row*4 + (c-DOF)] = 1.f/(1.f + expf(-val));
}

extern "C" void kernel_launch(void* const* d_in, const int* in_sizes, int n_in,
                              void* d_out, int out_size, void* d_ws, size_t ws_size,
                              hipStream_t stream)
{
    fp32p x      = (fp32p)d_in[0];
    fp32p mask   = (fp32p)d_in[1];
    fp32p enc_w1 = (fp32p)d_in[2];
    fp32p enc_b1 = (fp32p)d_in[3];
    fp32p enc_a1 = (fp32p)d_in[4];
    fp32p enc_w2 = (fp32p)d_in[5];
    fp32p enc_b2 = (fp32p)d_in[6];
    fp32p enc_a2 = (fp32p)d_in[7];
    fp32p rel_w1 = (fp32p)d_in[8];
    fp32p rel_b1 = (fp32p)d_in[9];
    fp32p rel_a  = (fp32p)d_in[10];
    fp32p rel_w2 = (fp32p)d_in[11];
    fp32p rel_b2 = (fp32p)d_in[12];
    fp32p ln_g   = (fp32p)d_in[13];
    fp32p ln_b   = (fp32p)d_in[14];
    fp32p wq     = (fp32p)d_in[15];
    fp32p bq     = (fp32p)d_in[16];
    fp32p wk     = (fp32p)d_in[17];
    fp32p bk     = (fp32p)d_in[18];
    fp32p wv     = (fp32p)d_in[19];
    fp32p bv     = (fp32p)d_in[20];
    fp32p wo     = (fp32p)d_in[21];
    fp32p bo     = (fp32p)d_in[22];
    fp32p fw1    = (fp32p)d_in[23];
    fp32p fb1    = (fp32p)d_in[24];
    fp32p fa     = (fp32p)d_in[25];
    fp32p fw2    = (fp32p)d_in[26];
    fp32p fb2    = (fp32p)d_in[27];
    fp32p dec_w1 = (fp32p)d_in[28];
    fp32p dec_b1 = (fp32p)d_in[29];
    fp32p dec_a  = (fp32p)d_in[30];
    fp32p dec_w2 = (fp32p)d_in[31];
    fp32p dec_b2 = (fp32p)d_in[32];

    char* wsb = (char*)d_ws;
    bf16*  Ebf = (bf16*)(wsb + E_OFF);
    float* h   = (float*)(wsb + H_OFF);
    bf16*  hn  = (bf16*)(wsb + HN_OFF);
    bf16*  q   = (bf16*)(wsb + Q_OFF);
    bf16*  k   = (bf16*)(wsb + K_OFF);
    bf16*  v   = (bf16*)(wsb + V_OFF);
    bf16*  cat = q;
    bf16*  mid = q;            // ffn half, spans q+k slots (8 MB)
    bf16*  hb  = v;
    float* y   = (float*)q;

    dim3 gD(DMODEL/128, MTOK/128);   // 4 x 32
    dim3 gF(1024/128, MTOK/128);     // 8 x 32

    // encoder
    k_concat<<<(MTOK*2*DOF+255)/256, 256, 0, stream>>>(x, mask, cat);
    k_gemm<1,0,1,0><<<gD,256,0,stream>>>(cat, 2*DOF, enc_w1, 0, DMODEL, enc_b1, 0, enc_a1, 0, nullptr, hn, DMODEL, MTOK, DMODEL, 2*DOF);
    k_gemm<1,0,1,1><<<gD,256,0,stream>>>(hn, DMODEL, enc_w2, 0, DMODEL, enc_b2, 0, enc_a2, 0, nullptr, h, DMODEL, MTOK, DMODEL, DMODEL);
    k_relemb<<<EROWS, 64, 0, stream>>>(rel_w1, rel_b1, rel_a, rel_w2, rel_b2, Ebf);

    for (int l = 0; l < NL; ++l) {
        size_t oW  = (size_t)l*DMODEL*DMODEL;
        size_t oB  = (size_t)l*DMODEL;
        size_t oF1 = (size_t)l*DMODEL*DFF;
        size_t oBF1= (size_t)l*DFF;
        size_t oF2 = (size_t)l*DFF*DMODEL;

        k_layernorm<<<MTOK, 256, 0, stream>>>(h, ln_g, ln_b, hn);
        k_gemm<0,0,1,0><<<gD,256,0,stream>>>(hn, DMODEL, wq, oW, DMODEL, bq, oB, nullptr, 0, nullptr, q, DMODEL, MTOK, DMODEL, DMODEL);
        k_gemm<0,0,1,0><<<gD,256,0,stream>>>(hn, DMODEL, wk, oW, DMODEL, bk, oB, nullptr, 0, nullptr, k, DMODEL, MTOK, DMODEL, DMODEL);
        k_gemm<0,0,1,0><<<gD,256,0,stream>>>(hn, DMODEL, wv, oW, DMODEL, bv, oB, nullptr, 0, nullptr, v, DMODEL, MTOK, DMODEL, DMODEL);
        k_attn<<<BB*NH*(TT/64), 256, 0, stream>>>(q, k, v, Ebf, hn);
        k_gemm<0,1,1,1><<<gD,256,0,stream>>>(hn, DMODEL, wo, oW, DMODEL, bo, oB, nullptr, 0, h, h, DMODEL, MTOK, DMODEL, DMODEL);
        k_layernorm<<<MTOK, 256, 0, stream>>>(h, ln_g, ln_b, hn);
        k_gemm<1,0,1,0><<<gF,256,0,stream>>>(hn, DMODEL, fw1, oF1, DFF, fb1, oBF1, fa, (size_t)l, nullptr, mid, 1024, MTOK, 1024, DMODEL);
        k_gemm<0,1,1,1><<<gD,256,0,stream>>>(mid, 1024, fw2, oF2, DMODEL, fb2, oB, nullptr, 0, h, h, DMODEL, MTOK, DMODEL, 1024);
        k_gemm<1,0,1,0><<<gF,256,0,stream>>>(hn, DMODEL, fw1, oF1 + 1024, DFF, fb1, oBF1 + 1024, fa, (size_t)l, nullptr, mid, 1024, MTOK, 1024, DMODEL);
        k_gemm<0,1,0,1><<<gD,256,0,stream>>>(mid, 1024, fw2, oF2 + (size_t)1024*DMODEL, DMODEL, nullptr, 0, nullptr, 0, h, h, DMODEL, MTOK, DMODEL, 1024);
    }

    // decoder
    k_cast<<<(MTOK*DMODEL+255)/256, 256, 0, stream>>>(h, hb);
    k_gemm<1,0,1,0><<<gD,256,0,stream>>>(hb, DMODEL, dec_w1, 0, DMODEL, dec_b1, 0, dec_a, 0, nullptr, hn, DMODEL, MTOK, DMODEL, DMODEL);
    {
        dim3 g2(1, MTOK/128);
        k_gemm<0,0,1,1><<<g2,256,0,stream>>>(hn, DMODEL, dec_w2, 0, DOF+4, dec_b2, 0, nullptr, 0, nullptr, y, DOF+4, MTOK, DOF+4, DMODEL);
    }
    k_out<<<(MTOK*73+255)/256, 256, 0, stream>>>(y, (float*)d_out);
}

// Round 10
// 1757.520 us; speedup vs baseline: 3.7328x; 3.7328x over previous
//
#include <hip/hip_runtime.h>
#include <hip/hip_bf16.h>

#define DOF 69
#define NL 6
#define NH 8
#define DMODEL 512
#define DFF 2048
#define HD 64
#define BB 8
#define TT 512
#define MTOK (BB*TT)   // 4096
#define EROWS 1040     // 2T-1 = 1023, padded
#define CATP 160       // padded concat pitch (K=138 rounded past 32-step reach)

// workspace layout (bytes) — 24.5 MB total
#define E_OFF     4096u
#define H_OFF     (512u*1024u)
#define HN_OFF    (H_OFF + 8u*1024u*1024u)
#define Q_OFF     (HN_OFF + 4u*1024u*1024u)
#define K_OFF     (Q_OFF + 4u*1024u*1024u)
#define V_OFF     (K_OFF + 4u*1024u*1024u)

typedef const float* fp32p;
typedef __hip_bfloat16 bf16;
typedef const bf16* bf16p;
typedef __attribute__((ext_vector_type(8))) short bf16x8;  // 8 bf16 (4 VGPRs)
typedef __attribute__((ext_vector_type(4))) float f32x4;   // 4 fp32 acc

__device__ __forceinline__ float b2f(bf16 x){ return __bfloat162float(x); }

// ---------------- concat(x, mask) fp32 -> bf16, zero-padded to pitch CATP ----------------
__global__ __launch_bounds__(256)
void k_concat(fp32p x, fp32p mask, bf16* __restrict__ out){
    int idx = blockIdx.x*256 + threadIdx.x;
    if (idx >= MTOK*CATP) return;
    int row = idx / CATP, c = idx - row*CATP;
    float v = 0.f;
    if (c < DOF) v = x[(size_t)row*DOF + c];
    else if (c < 2*DOF) v = mask[(size_t)row*DOF + (c - DOF)];
    out[idx] = __float2bfloat16(v);
}

// ---------------- cast fp32 -> bf16 ----------------
__global__ __launch_bounds__(256)
void k_cast(const float* __restrict__ in, bf16* __restrict__ out){
    int idx = blockIdx.x*256 + threadIdx.x;
    if (idx >= MTOK*DMODEL) return;
    out[idx] = __float2bfloat16(in[idx]);
}

// ---------------- barrier-free MFMA GEMM ----------------
// C = epi(A @ B[boff..] + bias[biasoff..]); A bf16 (M x K) lda (lda%8==0),
// B fp32 (K x N) ldb. Per-wave 64(M)x32(N) tile; block = 4 waves stacked in M
// (256 rows). No LDS, no barriers: A frags loaded bf16x8 direct, B frags as
// 16 independent fp32 dwords/K-step from L2-resident weights, cvt in-register.
// KT: K-tail clamp (A must be zero-padded past K). N-tail via col clamp + guard.
template<int PRELU, int RESID, int HASBIAS, int OUTF32, int KT>
__global__ __launch_bounds__(256)
void k_gemm(bf16p A, int lda,
            fp32p Bw, size_t boff, int ldb,
            fp32p bias, size_t biasoff,
            fp32p alpha, size_t aidx,
            const float* __restrict__ resid,
            void* __restrict__ Cout, int ldc,
            int M, int N, int K)
{
    const int tid  = threadIdx.x;
    const int w    = tid >> 6;
    const int lane = tid & 63;
    const int qd   = lane >> 4;       // quad 0..3
    const int cl   = lane & 15;       // 0..15
    const int bm   = blockIdx.y * 256 + w * 64;
    const int bn   = blockIdx.x * 32;

    const int c0 = min(bn + cl,      N-1);
    const int c1 = min(bn + 16 + cl, N-1);

    f32x4 acc[4][2] = {};

    for (int k0 = 0; k0 < K; k0 += 32) {
        bf16x8 aF[4];
        #pragma unroll
        for (int mt = 0; mt < 4; ++mt)
            aF[mt] = *(const bf16x8*)(A + (size_t)(bm + mt*16 + cl)*lda + k0 + qd*8);

        bf16 t0[8], t1[8];
        #pragma unroll
        for (int e = 0; e < 8; ++e) {
            int kk = k0 + qd*8 + e;
            float v0, v1;
            if (KT) {
                int kc = min(kk, K-1);
                bool ok = (kk < K);
                v0 = ok ? Bw[boff + (size_t)kc*ldb + c0] : 0.f;
                v1 = ok ? Bw[boff + (size_t)kc*ldb + c1] : 0.f;
            } else {
                v0 = Bw[boff + (size_t)kk*ldb + c0];
                v1 = Bw[boff + (size_t)kk*ldb + c1];
            }
            t0[e] = __float2bfloat16(v0);
            t1[e] = __float2bfloat16(v1);
        }
        bf16x8 bF0 = *(bf16x8*)t0;
        bf16x8 bF1 = *(bf16x8*)t1;

        #pragma unroll
        for (int mt = 0; mt < 4; ++mt) {
            acc[mt][0] = __builtin_amdgcn_mfma_f32_16x16x32_bf16(aF[mt], bF0, acc[mt][0], 0, 0, 0);
            acc[mt][1] = __builtin_amdgcn_mfma_f32_16x16x32_bf16(aF[mt], bF1, acc[mt][1], 0, 0, 0);
        }
    }

    const float alp = PRELU ? alpha[aidx] : 0.f;
    #pragma unroll
    for (int nt = 0; nt < 2; ++nt) {
        int col = bn + nt*16 + cl;
        if (col < N) {
            float bv = HASBIAS ? bias[biasoff + col] : 0.f;
            #pragma unroll
            for (int mt = 0; mt < 4; ++mt) {
                #pragma unroll
                for (int r = 0; r < 4; ++r) {
                    int row = bm + mt*16 + qd*4 + r;
                    float c = acc[mt][nt][r] + bv;
                    if (PRELU) c = (c >= 0.f) ? c : alp*c;
                    if (RESID) c += resid[(size_t)row*ldc + col];
                    if (OUTF32) ((float*)Cout)[(size_t)row*ldc + col] = c;
                    else ((bf16*)Cout)[(size_t)row*ldc + col] = __float2bfloat16(c);
                }
            }
        }
    }
}

// ---------------- LayerNorm: fp32 in -> bf16 out ----------------
__global__ __launch_bounds__(256)
void k_layernorm(const float* __restrict__ x, fp32p g, fp32p b, bf16* __restrict__ out){
    __shared__ float red[256];
    const int row = blockIdx.x, tid = threadIdx.x;
    const float* xr = x + (size_t)row*DMODEL;
    float x0 = xr[tid], x1 = xr[tid+256];
    red[tid] = x0 + x1; __syncthreads();
    for (int o = 128; o > 0; o >>= 1) { if (tid < o) red[tid] += red[tid+o]; __syncthreads(); }
    float mean = red[0] * (1.f/DMODEL);
    __syncthreads();
    float d0 = x0 - mean, d1 = x1 - mean;
    red[tid] = d0*d0 + d1*d1; __syncthreads();
    for (int o = 128; o > 0; o >>= 1) { if (tid < o) red[tid] += red[tid+o]; __syncthreads(); }
    float inv = rsqrtf(red[0]*(1.f/DMODEL) + 1e-6f);
    out[(size_t)row*DMODEL + tid]     = __float2bfloat16(d0*inv*g[tid]     + b[tid]);
    out[(size_t)row*DMODEL + tid+256] = __float2bfloat16(d1*inv*g[tid+256] + b[tid+256]);
}

// ---------------- relative embedding E: (EROWS, HD) bf16, zero-padded ----------------
__global__ __launch_bounds__(64)
void k_relemb(fp32p w1, fp32p b1, fp32p a, fp32p w2, fp32p b2, bf16* __restrict__ Ebf){
    __shared__ float sH[DMODEL];
    const int r = blockIdx.x, tid = threadIdx.x;
    if (r >= 2*TT - 1) { Ebf[(size_t)r*HD + tid] = __float2bfloat16(0.f); return; }
    const float dist = (float)(r - (TT-1));
    const float al = a[0];
    for (int d = tid; d < DMODEL; d += 64) {
        float hv = dist * w1[d] + b1[d];
        sH[d] = (hv >= 0.f) ? hv : al*hv;
    }
    __syncthreads();
    float acc = b2[tid];
    for (int d = 0; d < DMODEL; ++d) acc += sH[d] * w2[(size_t)d*HD + tid];
    Ebf[(size_t)r*HD + tid] = __float2bfloat16(acc);
}

// ---------------- MFMA flash attention with relative-position skew ----------------
__global__ __launch_bounds__(256)
void k_attn(bf16p q, bf16p k, bf16p v, bf16p Ebf, bf16* __restrict__ o)
{
    __shared__ bf16  sVT[64][68];        // V^T tile: [d][j_local]
    __shared__ float sQE[4][16][100];    // per-wave qe tile
    __shared__ bf16  sP[4][16][68];      // per-wave P tile

    const int bid  = blockIdx.x;
    const int itile = bid & 7;
    const int h    = (bid >> 3) & 7;
    const int b    = bid >> 6;
    const int tid  = threadIdx.x;
    const int w    = tid >> 6;
    const int lane = tid & 63;
    const int qd   = lane >> 4;
    const int cl   = lane & 15;

    const int I = itile*64 + w*16;
    const size_t bh = ((size_t)b*TT)*DMODEL + (size_t)h*HD;

    bf16x8 qa0, qa1;
    {
        const bf16* qrow = q + bh + (size_t)(I + cl)*DMODEL;
        qa0 = *(const bf16x8*)(qrow + qd*8);
        qa1 = *(const bf16x8*)(qrow + 32 + qd*8);
    }

    f32x4 Oacc[4] = {};
    float m_i[4], l_i[4];
    #pragma unroll
    for (int r = 0; r < 4; ++r) { m_i[r] = -1e30f; l_i[r] = 0.f; }
    const float scale = 0.125f;

    for (int J = 0; J < TT; J += 64) {
        {
            int j = tid >> 2, dc = (tid & 3) * 16;
            const bf16* vrow = v + bh + (size_t)(J + j)*DMODEL + dc;
            bf16x8 v0 = *(const bf16x8*)(vrow);
            bf16x8 v1 = *(const bf16x8*)(vrow + 8);
            #pragma unroll
            for (int e = 0; e < 8; ++e) sVT[dc + e][j]     = ((const bf16*)&v0)[e];
            #pragma unroll
            for (int e = 0; e < 8; ++e) sVT[dc + 8 + e][j] = ((const bf16*)&v1)[e];
        }
        __syncthreads();

        f32x4 S[4];
        #pragma unroll
        for (int js = 0; js < 4; ++js) {
            const bf16* krow = k + bh + (size_t)(J + js*16 + cl)*DMODEL;
            bf16x8 kb0 = *(const bf16x8*)(krow + qd*8);
            bf16x8 kb1 = *(const bf16x8*)(krow + 32 + qd*8);
            f32x4 acc = {};
            acc = __builtin_amdgcn_mfma_f32_16x16x32_bf16(qa0, kb0, acc, 0, 0, 0);
            acc = __builtin_amdgcn_mfma_f32_16x16x32_bf16(qa1, kb1, acc, 0, 0, 0);
            S[js] = acc;
        }

        const int rbase = J - I + 496;
        #pragma unroll
        for (int nt = 0; nt < 6; ++nt) {
            const bf16* erow = Ebf + (size_t)(rbase + nt*16 + cl)*HD;
            bf16x8 eb0 = *(const bf16x8*)(erow + qd*8);
            bf16x8 eb1 = *(const bf16x8*)(erow + 32 + qd*8);
            f32x4 acc = {};
            acc = __builtin_amdgcn_mfma_f32_16x16x32_bf16(qa0, eb0, acc, 0, 0, 0);
            acc = __builtin_amdgcn_mfma_f32_16x16x32_bf16(qa1, eb1, acc, 0, 0, 0);
            #pragma unroll
            for (int r = 0; r < 4; ++r)
                sQE[w][qd*4 + r][nt*16 + cl] = acc[r];
        }

        float mnew[4];
        #pragma unroll
        for (int r = 0; r < 4; ++r) mnew[r] = m_i[r];
        #pragma unroll
        for (int js = 0; js < 4; ++js) {
            #pragma unroll
            for (int r = 0; r < 4; ++r) {
                int idx = js*16 + cl - (qd*4 + r) + 15;
                float s = S[js][r] + sQE[w][qd*4 + r][idx];
                S[js][r] = s;
                mnew[r] = fmaxf(mnew[r], s);
            }
        }
        #pragma unroll
        for (int r = 0; r < 4; ++r) {
            float mv = mnew[r];
            mv = fmaxf(mv, __shfl_xor(mv, 1));
            mv = fmaxf(mv, __shfl_xor(mv, 2));
            mv = fmaxf(mv, __shfl_xor(mv, 4));
            mv = fmaxf(mv, __shfl_xor(mv, 8));
            mnew[r] = mv;
        }
        float alpha[4], rsum[4];
        #pragma unroll
        for (int r = 0; r < 4; ++r) {
            alpha[r] = expf((m_i[r] - mnew[r]) * scale);
            m_i[r] = mnew[r];
            rsum[r] = 0.f;
        }
        #pragma unroll
        for (int js = 0; js < 4; ++js) {
            #pragma unroll
            for (int r = 0; r < 4; ++r) {
                float p = expf((S[js][r] - m_i[r]) * scale);
                rsum[r] += p;
                sP[w][qd*4 + r][js*16 + cl] = __float2bfloat16(p);
            }
        }
        #pragma unroll
        for (int r = 0; r < 4; ++r) {
            float sv = rsum[r];
            sv += __shfl_xor(sv, 1);
            sv += __shfl_xor(sv, 2);
            sv += __shfl_xor(sv, 4);
            sv += __shfl_xor(sv, 8);
            l_i[r] = l_i[r]*alpha[r] + sv;
        }

        bf16x8 pa0, pa1;
        {
            const bf16* pr = &sP[w][cl][0];
            #pragma unroll
            for (int e = 0; e < 8; ++e) ((short*)&pa0)[e] = ((const short*)pr)[qd*8 + e];
            #pragma unroll
            for (int e = 0; e < 8; ++e) ((short*)&pa1)[e] = ((const short*)pr)[32 + qd*8 + e];
        }

        #pragma unroll
        for (int nt = 0; nt < 4; ++nt) {
            #pragma unroll
            for (int r = 0; r < 4; ++r) Oacc[nt][r] *= alpha[r];
            bf16x8 vb0, vb1;
            const bf16* vr = &sVT[nt*16 + cl][0];
            #pragma unroll
            for (int e = 0; e < 8; ++e) ((short*)&vb0)[e] = ((const short*)vr)[qd*8 + e];
            #pragma unroll
            for (int e = 0; e < 8; ++e) ((short*)&vb1)[e] = ((const short*)vr)[32 + qd*8 + e];
            Oacc[nt] = __builtin_amdgcn_mfma_f32_16x16x32_bf16(pa0, vb0, Oacc[nt], 0, 0, 0);
            Oacc[nt] = __builtin_amdgcn_mfma_f32_16x16x32_bf16(pa1, vb1, Oacc[nt], 0, 0, 0);
        }
        __syncthreads();
    }

    #pragma unroll
    for (int nt = 0; nt < 4; ++nt) {
        #pragma unroll
        for (int r = 0; r < 4; ++r) {
            int row = qd*4 + r;
            float val = Oacc[nt][r] / l_i[r];
            o[bh + (size_t)(I + row)*DMODEL + nt*16 + cl] = __float2bfloat16(val);
        }
    }
}

// ---------------- output split + sigmoid (fp32 out) ----------------
__global__ __launch_bounds__(256)
void k_out(const float* __restrict__ y, float* __restrict__ out){
    int idx = blockIdx.x*256 + threadIdx.x;
    if (idx >= MTOK*73) return;
    int row = idx / 73, c = idx - row*73;
    float val = y[idx];
    if (c < DOF) out[(size_t)row*DOF + c] = val;
    else out[(size_t)MTOK*DOF + row*4 + (c-DOF)] = 1.f/(1.f + expf(-val));
}

extern "C" void kernel_launch(void* const* d_in, const int* in_sizes, int n_in,
                              void* d_out, int out_size, void* d_ws, size_t ws_size,
                              hipStream_t stream)
{
    fp32p x      = (fp32p)d_in[0];
    fp32p mask   = (fp32p)d_in[1];
    fp32p enc_w1 = (fp32p)d_in[2];
    fp32p enc_b1 = (fp32p)d_in[3];
    fp32p enc_a1 = (fp32p)d_in[4];
    fp32p enc_w2 = (fp32p)d_in[5];
    fp32p enc_b2 = (fp32p)d_in[6];
    fp32p enc_a2 = (fp32p)d_in[7];
    fp32p rel_w1 = (fp32p)d_in[8];
    fp32p rel_b1 = (fp32p)d_in[9];
    fp32p rel_a  = (fp32p)d_in[10];
    fp32p rel_w2 = (fp32p)d_in[11];
    fp32p rel_b2 = (fp32p)d_in[12];
    fp32p ln_g   = (fp32p)d_in[13];
    fp32p ln_b   = (fp32p)d_in[14];
    fp32p wq     = (fp32p)d_in[15];
    fp32p bq     = (fp32p)d_in[16];
    fp32p wk     = (fp32p)d_in[17];
    fp32p bk     = (fp32p)d_in[18];
    fp32p wv     = (fp32p)d_in[19];
    fp32p bv     = (fp32p)d_in[20];
    fp32p wo     = (fp32p)d_in[21];
    fp32p bo     = (fp32p)d_in[22];
    fp32p fw1    = (fp32p)d_in[23];
    fp32p fb1    = (fp32p)d_in[24];
    fp32p fa     = (fp32p)d_in[25];
    fp32p fw2    = (fp32p)d_in[26];
    fp32p fb2    = (fp32p)d_in[27];
    fp32p dec_w1 = (fp32p)d_in[28];
    fp32p dec_b1 = (fp32p)d_in[29];
    fp32p dec_a  = (fp32p)d_in[30];
    fp32p dec_w2 = (fp32p)d_in[31];
    fp32p dec_b2 = (fp32p)d_in[32];

    char* wsb = (char*)d_ws;
    bf16*  Ebf = (bf16*)(wsb + E_OFF);
    float* h   = (float*)(wsb + H_OFF);
    bf16*  hn  = (bf16*)(wsb + HN_OFF);
    bf16*  q   = (bf16*)(wsb + Q_OFF);
    bf16*  k   = (bf16*)(wsb + K_OFF);
    bf16*  v   = (bf16*)(wsb + V_OFF);
    bf16*  cat = q;            // encoder scratch (pitch CATP, 1.31 MB)
    bf16*  mid = q;            // ffn half, spans q+k slots (8 MB)
    bf16*  hb  = v;            // decoder bf16 cast of h
    float* y   = (float*)q;    // decoder logits fp32

    dim3 gD(DMODEL/32, MTOK/256);    // 16 x 16 = 256 blocks
    dim3 gF(1024/32, MTOK/256);      // 32 x 16 = 512 blocks

    // encoder
    k_concat<<<(MTOK*CATP+255)/256, 256, 0, stream>>>(x, mask, cat);
    k_gemm<1,0,1,0,1><<<gD,256,0,stream>>>(cat, CATP, enc_w1, 0, DMODEL, enc_b1, 0, enc_a1, 0, nullptr, hn, DMODEL, MTOK, DMODEL, 2*DOF);
    k_gemm<1,0,1,1,0><<<gD,256,0,stream>>>(hn, DMODEL, enc_w2, 0, DMODEL, enc_b2, 0, enc_a2, 0, nullptr, h, DMODEL, MTOK, DMODEL, DMODEL);
    k_relemb<<<EROWS, 64, 0, stream>>>(rel_w1, rel_b1, rel_a, rel_w2, rel_b2, Ebf);

    for (int l = 0; l < NL; ++l) {
        size_t oW  = (size_t)l*DMODEL*DMODEL;
        size_t oB  = (size_t)l*DMODEL;
        size_t oF1 = (size_t)l*DMODEL*DFF;
        size_t oBF1= (size_t)l*DFF;
        size_t oF2 = (size_t)l*DFF*DMODEL;

        k_layernorm<<<MTOK, 256, 0, stream>>>(h, ln_g, ln_b, hn);
        k_gemm<0,0,1,0,0><<<gD,256,0,stream>>>(hn, DMODEL, wq, oW, DMODEL, bq, oB, nullptr, 0, nullptr, q, DMODEL, MTOK, DMODEL, DMODEL);
        k_gemm<0,0,1,0,0><<<gD,256,0,stream>>>(hn, DMODEL, wk, oW, DMODEL, bk, oB, nullptr, 0, nullptr, k, DMODEL, MTOK, DMODEL, DMODEL);
        k_gemm<0,0,1,0,0><<<gD,256,0,stream>>>(hn, DMODEL, wv, oW, DMODEL, bv, oB, nullptr, 0, nullptr, v, DMODEL, MTOK, DMODEL, DMODEL);
        k_attn<<<BB*NH*(TT/64), 256, 0, stream>>>(q, k, v, Ebf, hn);
        k_gemm<0,1,1,1,0><<<gD,256,0,stream>>>(hn, DMODEL, wo, oW, DMODEL, bo, oB, nullptr, 0, h, h, DMODEL, MTOK, DMODEL, DMODEL);
        k_layernorm<<<MTOK, 256, 0, stream>>>(h, ln_g, ln_b, hn);
        k_gemm<1,0,1,0,0><<<gF,256,0,stream>>>(hn, DMODEL, fw1, oF1, DFF, fb1, oBF1, fa, (size_t)l, nullptr, mid, 1024, MTOK, 1024, DMODEL);
        k_gemm<0,1,1,1,0><<<gD,256,0,stream>>>(mid, 1024, fw2, oF2, DMODEL, fb2, oB, nullptr, 0, h, h, DMODEL, MTOK, DMODEL, 1024);
        k_gemm<1,0,1,0,0><<<gF,256,0,stream>>>(hn, DMODEL, fw1, oF1 + 1024, DFF, fb1, oBF1 + 1024, fa, (size_t)l, nullptr, mid, 1024, MTOK, 1024, DMODEL);
        k_gemm<0,1,0,1,0><<<gD,256,0,stream>>>(mid, 1024, fw2, oF2 + (size_t)1024*DMODEL, DMODEL, nullptr, 0, nullptr, 0, h, h, DMODEL, MTOK, DMODEL, 1024);
    }

    // decoder
    k_cast<<<(MTOK*DMODEL+255)/256, 256, 0, stream>>>(h, hb);
    k_gemm<1,0,1,0,0><<<gD,256,0,stream>>>(hb, DMODEL, dec_w1, 0, DMODEL, dec_b1, 0, dec_a, 0, nullptr, hn, DMODEL, MTOK, DMODEL, DMODEL);
    {
        dim3 g2((DOF+4+31)/32, MTOK/256);   // 3 x 16
        k_gemm<0,0,1,1,0><<<g2,256,0,stream>>>(hn, DMODEL, dec_w2, 0, DOF+4, dec_b2, 0, nullptr, 0, nullptr, y, DOF+4, MTOK, DOF+4, DMODEL);
    }
    k_out<<<(MTOK*73+255)/256, 256, 0, stream>>>(y, (float*)d_out);
}